// Round 1
// baseline (4866.092 us; speedup 1.0000x reference)
//
#include <hip/hip_runtime.h>

// ============================================================
// CustomUltrasoundViT: 12-layer ViT (B=4, S=1025->pad 1152, D=768, H=12, HD=64,
// MLP=3072) + cross-attn + 3 heads. bf16 MFMA GEMMs, fp32 residual stream.
// ============================================================

typedef __attribute__((ext_vector_type(8))) short short8;
typedef __attribute__((ext_vector_type(4))) float floatx4;

#define EPI_BF16  0
#define EPI_BIAS  1
#define EPI_QKV   2
#define EPI_RES   3
#define EPI_GELU  4
#define EPI_PATCH 5

__device__ __forceinline__ short f2bf(float f) {
    union { float f; unsigned u; } x; x.f = f;
    return (short)((x.u + 0x7fffu + ((x.u >> 16) & 1u)) >> 16);
}
__device__ __forceinline__ float bf2f(short s) {
    union { unsigned u; float f; } x; x.u = ((unsigned)(unsigned short)s) << 16;
    return x.f;
}
__device__ __forceinline__ float gelu_f(float x) {
    return 0.5f * x * (1.f + erff(x * 0.70710678118654752f));
}
__device__ __forceinline__ void gload_lds16(const void* g, void* l) {
    __builtin_amdgcn_global_load_lds((const __attribute__((address_space(1))) void*)g,
                                     (__attribute__((address_space(3))) void*)l, 16, 0, 0);
}

// ------------------------------------------------------------
// gemm_bt: C[M,N] = A[M,K] @ BT[N,K]^T   (both row-major bf16-as-short)
// BM=128 tile, BN=128 (4 waves 2x2) or 64 (2 waves stacked), BK=32.
// z-dim batching: ptr += (z/zdiv)*s1 + (z%zdiv)*s2 for A, B, O.
// ------------------------------------------------------------
template<int BN, int EPI>
__global__ __launch_bounds__(BN == 128 ? 256 : 128)
void gemm_bt(const short* __restrict__ A, int lda, long az1, long az2,
             const short* __restrict__ Bt, int ldb, long bz1, long bz2,
             int K, int zdiv,
             short* __restrict__ O, int ldo, long oz1, long oz2,
             const float* __restrict__ bias0, const float* __restrict__ bias1,
             const float* __restrict__ bias2, float* __restrict__ hres,
             const float* __restrict__ pos,
             short* __restrict__ kout, short* __restrict__ vout)
{
    constexpr int NT = (BN == 128) ? 256 : 128;
    constexpr int ALOADS = 8192 / (NT * 16);        // A tile: 128x32x2B
    constexpr int BLOADS = (BN * 64) / (NT * 16);   // B tile: BNx32x2B
    __shared__ __align__(16) short As[128 * 32];
    __shared__ __align__(16) short Bs[BN * 32];

    const int tid = threadIdx.x;
    const int z = blockIdx.z;
    const int zq = z / zdiv, zr = z - zq * zdiv;
    A  += (long)zq * az1 + (long)zr * az2;
    Bt += (long)zq * bz1 + (long)zr * bz2;

    const int m0 = blockIdx.x * 128, n0 = blockIdx.y * BN;
    const int wave = tid >> 6, lane = tid & 63;
    const int quad = lane >> 4, l15 = lane & 15;
    const int wm = (BN == 128) ? (wave >> 1) : wave;
    const int wn = (BN == 128) ? (wave & 1) : 0;
    const int srow = tid >> 2;          // staging row within chunk
    const int scol = (tid & 3) * 8;     // staging col (elements)

    floatx4 acc[4][4];
    #pragma unroll
    for (int i = 0; i < 4; i++)
        #pragma unroll
        for (int j = 0; j < 4; j++)
            acc[i][j] = floatx4{0.f, 0.f, 0.f, 0.f};

    char* asBase = (char*)As + wave * 1024;   // wave-uniform LDS dest base
    char* bsBase = (char*)Bs + wave * 1024;
    const short* Ag = A + (long)(m0 + srow) * lda + scol;
    const short* Bg = Bt + (long)(n0 + srow) * ldb + scol;

    for (int k0 = 0; k0 < K; k0 += 32) {
        #pragma unroll
        for (int i = 0; i < ALOADS; i++)
            gload_lds16(Ag + (long)(i * (NT / 4)) * lda + k0, asBase + i * (NT * 16));
        #pragma unroll
        for (int i = 0; i < BLOADS; i++)
            gload_lds16(Bg + (long)(i * (NT / 4)) * ldb + k0, bsBase + i * (NT * 16));
        __syncthreads();
        short8 af[4], bfr[4];
        #pragma unroll
        for (int i = 0; i < 4; i++)
            af[i] = *(const short8*)&As[(wm * 64 + i * 16 + l15) * 32 + quad * 8];
        #pragma unroll
        for (int j = 0; j < 4; j++)
            bfr[j] = *(const short8*)&Bs[(wn * 64 + j * 16 + l15) * 32 + quad * 8];
        #pragma unroll
        for (int i = 0; i < 4; i++)
            #pragma unroll
            for (int j = 0; j < 4; j++)
                acc[i][j] = __builtin_amdgcn_mfma_f32_16x16x32_bf16(af[i], bfr[j], acc[i][j], 0, 0, 0);
        __syncthreads();
    }

    O += (long)zq * oz1 + (long)zr * oz2;
    const int mb = m0 + wm * 64 + quad * 4;
    const int nb = n0 + wn * 64 + l15;
    #pragma unroll
    for (int i = 0; i < 4; i++) {
        #pragma unroll
        for (int j = 0; j < 4; j++) {
            #pragma unroll
            for (int r = 0; r < 4; r++) {
                const int m = mb + i * 16 + r;
                const int n = nb + j * 16;
                const float c = acc[i][j][r];
                if constexpr (EPI == EPI_BF16) {
                    O[(long)m * ldo + n] = f2bf(c);
                } else if constexpr (EPI == EPI_BIAS) {
                    O[(long)m * ldo + n] = f2bf(c + bias0[n]);
                } else if constexpr (EPI == EPI_QKV) {
                    if (n < 768)            O[(long)m * 768 + n]            = f2bf((c + bias0[n]) * 0.125f);
                    else if (n < 1536)      kout[(long)m * 768 + (n - 768)]  = f2bf(c + bias1[n - 768]);
                    else                    vout[(long)m * 768 + (n - 1536)] = f2bf(c + bias2[n - 1536]);
                } else if constexpr (EPI == EPI_RES) {
                    hres[(long)m * 768 + n] += c + bias0[n];
                } else if constexpr (EPI == EPI_GELU) {
                    O[(long)m * ldo + n] = f2bf(gelu_f(c + bias0[n]));
                } else if constexpr (EPI == EPI_PATCH) {
                    const int tok = m % 1152;
                    float v = 0.f;
                    if (tok >= 1 && tok < 1025)
                        v = c + bias0[n] + pos[(long)tok * 768 + n];
                    hres[(long)m * 768 + n] = v;
                }
            }
        }
    }
}

// ------------------------------------------------------------
// weight transpose + fp32->bf16: out[(rowoff+n)*K + k] = in[k*N + n]
// grid (K/32, N/32, L), block 256
// ------------------------------------------------------------
__global__ void wtrans(const float* __restrict__ in, long inls, int K, int N,
                       short* __restrict__ out, long outls, int rowoff)
{
    in  += (long)blockIdx.z * inls;
    out += (long)blockIdx.z * outls;
    const int k0 = blockIdx.x * 32, n0 = blockIdx.y * 32;
    const int tx = threadIdx.x & 31, ty = threadIdx.x >> 5;  // ty: 0..7
    __shared__ float t[32][33];
    #pragma unroll
    for (int i = 0; i < 4; i++)
        t[ty + i * 8][tx] = in[(long)(k0 + ty + i * 8) * N + n0 + tx];
    __syncthreads();
    #pragma unroll
    for (int i = 0; i < 4; i++)
        out[(long)(rowoff + n0 + ty + i * 8) * K + k0 + tx] = f2bf(t[tx][ty + i * 8]);
}

__global__ void f2b_k(const float* __restrict__ in, short* __restrict__ out, long n)
{
    long gid = (long)blockIdx.x * 256 + threadIdx.x;
    if (gid < n) out[gid] = f2bf(in[gid]);
}

// patch gather: A[m][k] = x[b][c][py*16+i][px*16+j]; m=b*1152+tok, k=c*256+i*16+j
__global__ void patch_gather(const float* __restrict__ x, short* __restrict__ out)
{
    long gid = (long)blockIdx.x * 256 + threadIdx.x;   // 4608*768 total
    int m = (int)(gid / 768), k = (int)(gid % 768);
    int b = m / 1152, tok = m % 1152;
    short v = 0;
    if (tok >= 1 && tok < 1025) {
        int pidx = tok - 1, py = pidx >> 5, px = pidx & 31;
        int c = k >> 8, rem = k & 255, ii = rem >> 4, jj = rem & 15;
        float f = x[((long)(b * 3 + c) * 512 + py * 16 + ii) * 512 + px * 16 + jj];
        v = f2bf(f);
    }
    out[gid] = v;
}

__global__ void cls_fix(const float* __restrict__ cls, const float* __restrict__ pos,
                        float* __restrict__ h)
{
    int t = blockIdx.x * 256 + threadIdx.x;   // 4*768
    if (t >= 4 * 768) return;
    int b = t / 768, d = t % 768;
    h[(long)b * 1152 * 768 + d] = cls[d] + pos[d];
}

// LayerNorm fp32 -> bf16 out; one wave per row, 4 rows/block
__global__ void ln_k(const float* __restrict__ h, const float* __restrict__ g,
                     const float* __restrict__ bta, short* __restrict__ out)
{
    int row = blockIdx.x * 4 + (threadIdx.x >> 6);
    int lane = threadIdx.x & 63;
    const float* hr = h + (long)row * 768;
    float v[12], s = 0.f;
    #pragma unroll
    for (int i = 0; i < 12; i++) { v[i] = hr[i * 64 + lane]; s += v[i]; }
    #pragma unroll
    for (int o = 32; o > 0; o >>= 1) s += __shfl_xor(s, o, 64);
    float mean = s * (1.f / 768.f);
    float ss = 0.f;
    #pragma unroll
    for (int i = 0; i < 12; i++) { float d = v[i] - mean; ss += d * d; }
    #pragma unroll
    for (int o = 32; o > 0; o >>= 1) ss += __shfl_xor(ss, o, 64);
    float rstd = rsqrtf(ss * (1.f / 768.f) + 1e-5f);
    #pragma unroll
    for (int i = 0; i < 12; i++) {
        int col = i * 64 + lane;
        out[(long)row * 768 + col] = f2bf((v[i] - mean) * rstd * g[col] + bta[col]);
    }
}

// softmax over bf16 score rows (in-place), mask j>=1025; one wave per row
__global__ void softmax_k(short* __restrict__ sb)
{
    int row = blockIdx.x * 4 + (threadIdx.x >> 6);   // < 48*1152
    int lane = threadIdx.x & 63;
    short* sr = sb + (long)row * 1152;
    int i = row % 1152;
    if (i >= 1025) {
        #pragma unroll
        for (int t = 0; t < 18; t++) sr[t * 64 + lane] = 0;
        return;
    }
    float xv[17], mx = -1e30f;
    #pragma unroll
    for (int t = 0; t < 17; t++) {
        int j = t * 64 + lane;
        xv[t] = (j < 1025) ? bf2f(sr[j]) : -1e30f;
        mx = fmaxf(mx, xv[t]);
    }
    #pragma unroll
    for (int o = 32; o > 0; o >>= 1) mx = fmaxf(mx, __shfl_xor(mx, o, 64));
    float s = 0.f;
    #pragma unroll
    for (int t = 0; t < 17; t++) {
        xv[t] = (xv[t] > -1e29f) ? __expf(xv[t] - mx) : 0.f;
        s += xv[t];
    }
    #pragma unroll
    for (int o = 32; o > 0; o >>= 1) s += __shfl_xor(s, o, 64);
    float inv = 1.f / s;
    #pragma unroll
    for (int t = 0; t < 17; t++) {
        int j = t * 64 + lane;
        sr[j] = (j < 1025) ? f2bf(xv[t] * inv) : (short)0;
    }
    sr[17 * 64 + lane] = 0;
}

// vt[bh][d][s] = v[(b*1152+s)*768 + h*64 + d]; grid (1152/64, 48), block 256
__global__ void vtrans(const short* __restrict__ v, short* __restrict__ vt)
{
    int bh = blockIdx.y, b = bh / 12, hh = bh % 12;
    int s0 = blockIdx.x * 64;
    int tx = threadIdx.x & 63, ty = threadIdx.x >> 6;  // ty: 0..3
    __shared__ short t[64][65];
    #pragma unroll
    for (int i = 0; i < 16; i++) {
        int sl = ty * 16 + i;
        t[sl][tx] = v[(long)(b * 1152 + s0 + sl) * 768 + hh * 64 + tx];
    }
    __syncthreads();
    #pragma unroll
    for (int i = 0; i < 16; i++) {
        int d = ty * 16 + i;
        vt[((long)bh * 64 + d) * 1152 + s0 + tx] = t[tx][d];
    }
}

// tiny head GEMM: out[bs*NO+n] = b2[n] + sum_k hid[m,k]*w2[k,n]
__global__ void logits_k(const short* __restrict__ hid, const float* __restrict__ w2,
                         const float* __restrict__ b2, float* __restrict__ o, int NO)
{
    int gid = blockIdx.x * 256 + threadIdx.x;
    if (gid >= 4100 * NO) return;
    int bs = gid / NO, n = gid % NO;
    int b = bs / 1025, s = bs % 1025;
    const short* hr = hid + (long)(b * 1152 + s) * 384;
    float acc = b2[n];
    for (int k = 0; k < 384; k++) acc += bf2f(hr[k]) * w2[k * NO + n];
    o[gid] = acc;
}

__global__ void feats_out(const float* __restrict__ h, float* __restrict__ o)
{
    int gid = blockIdx.x * 256 + threadIdx.x;   // 4*1025*192
    if (gid >= 4 * 1025 * 192) return;
    int row = gid / 192, c4 = gid % 192;
    int b = row / 1025, s = row % 1025;
    const float4* src = (const float4*)(h + (long)(b * 1152 + s) * 768) + c4;
    float4* dst = (float4*)(o + (long)row * 768) + c4;
    *dst = *src;
}

// ============================================================
extern "C" void kernel_launch(void* const* d_in, const int* in_sizes, int n_in,
                              void* d_out, int out_size, void* d_ws, size_t ws_size,
                              hipStream_t stream)
{
    const float* x       = (const float*)d_in[0];
    const float* conv_w  = (const float*)d_in[1];
    const float* conv_b  = (const float*)d_in[2];
    const float* cls_tok = (const float*)d_in[3];
    const float* pos_emb = (const float*)d_in[4];
    const float* ln1g = (const float*)d_in[5];
    const float* ln1b = (const float*)d_in[6];
    const float* wq = (const float*)d_in[7];
    const float* bq = (const float*)d_in[8];
    const float* wk = (const float*)d_in[9];
    const float* bk = (const float*)d_in[10];
    const float* wv = (const float*)d_in[11];
    const float* bv = (const float*)d_in[12];
    const float* wo = (const float*)d_in[13];
    const float* bo = (const float*)d_in[14];
    const float* ln2g = (const float*)d_in[15];
    const float* ln2b = (const float*)d_in[16];
    const float* w1 = (const float*)d_in[17];
    const float* b1 = (const float*)d_in[18];
    const float* w2 = (const float*)d_in[19];
    const float* b2 = (const float*)d_in[20];
    const float* cwq = (const float*)d_in[21];
    const float* cbq = (const float*)d_in[22];
    const float* cwk = (const float*)d_in[23];
    const float* cbk = (const float*)d_in[24];
    const float* cwv = (const float*)d_in[25];
    const float* cbv = (const float*)d_in[26];
    const float* cwo = (const float*)d_in[27];
    const float* cbo = (const float*)d_in[28];
    const float* fh_w1 = (const float*)d_in[29];
    const float* fh_b1 = (const float*)d_in[30];
    const float* fh_w2 = (const float*)d_in[31];
    const float* fh_b2 = (const float*)d_in[32];
    const float* vh_w1 = (const float*)d_in[33];
    const float* vh_b1 = (const float*)d_in[34];
    const float* vh_w2 = (const float*)d_in[35];
    const float* vh_b2 = (const float*)d_in[36];
    const float* ch_w1 = (const float*)d_in[37];
    const float* ch_b1 = (const float*)d_in[38];
    const float* ch_w2 = (const float*)d_in[39];
    const float* ch_b2 = (const float*)d_in[40];
    float* out = (float*)d_out;

    // ---- workspace carve-up (all 256B aligned) ----
    char* ws = (char*)d_ws;
    size_t off = 0;
    auto alc = [&](size_t b) { char* p = ws + off; off += (b + 255) & ~(size_t)255; return p; };
    float* h     = (float*)alc(4608L * 768 * 4);
    short* abuf  = (short*)alc(4608L * 768 * 2);
    short* gbuf  = (short*)alc(4608L * 3072 * 2);
    short* qb    = (short*)alc(4608L * 768 * 2);
    short* kb    = (short*)alc(4608L * 768 * 2);
    short* vb    = (short*)alc(4608L * 768 * 2);
    short* vt    = (short*)alc(48L * 64 * 1152 * 2);
    short* sbuf  = (short*)alc(48L * 1152 * 1152 * 2);
    short* ctx   = (short*)alc(4608L * 768 * 2);
    short* fbuf  = (short*)alc(4608L * 768 * 2);
    short* vfbuf = (short*)alc(4608L * 768 * 2);
    short* hid   = (short*)alc(4608L * 384 * 2);
    short* wqkvT = (short*)alc(12L * 2304 * 768 * 2);
    short* woT   = (short*)alc(12L * 768 * 768 * 2);
    short* w1T   = (short*)alc(12L * 3072 * 768 * 2);
    short* w2T   = (short*)alc(12L * 768 * 3072 * 2);
    short* convT = (short*)alc(768L * 768 * 2);
    short* cqkvT = (short*)alc(2304L * 768 * 2);
    short* coT   = (short*)alc(768L * 768 * 2);
    short* fh1T  = (short*)alc(384L * 768 * 2);
    short* vh1T  = (short*)alc(384L * 768 * 2);
    short* ch1T  = (short*)alc(384L * 768 * 2);
    short* dummy = (short*)d_ws;

    // ---- weight prep (bf16 transposed [N,K]) ----
    wtrans<<<dim3(24, 24, 12), 256, 0, stream>>>(wq, 589824L, 768, 768, wqkvT, 1769472L, 0);
    wtrans<<<dim3(24, 24, 12), 256, 0, stream>>>(wk, 589824L, 768, 768, wqkvT, 1769472L, 768);
    wtrans<<<dim3(24, 24, 12), 256, 0, stream>>>(wv, 589824L, 768, 768, wqkvT, 1769472L, 1536);
    wtrans<<<dim3(24, 24, 12), 256, 0, stream>>>(wo, 589824L, 768, 768, woT, 589824L, 0);
    wtrans<<<dim3(24, 96, 12), 256, 0, stream>>>(w1, 2359296L, 768, 3072, w1T, 2359296L, 0);
    wtrans<<<dim3(96, 24, 12), 256, 0, stream>>>(w2, 2359296L, 3072, 768, w2T, 2359296L, 0);
    wtrans<<<dim3(24, 24, 1), 256, 0, stream>>>(cwq, 0, 768, 768, cqkvT, 0, 0);
    wtrans<<<dim3(24, 24, 1), 256, 0, stream>>>(cwk, 0, 768, 768, cqkvT, 0, 768);
    wtrans<<<dim3(24, 24, 1), 256, 0, stream>>>(cwv, 0, 768, 768, cqkvT, 0, 1536);
    wtrans<<<dim3(24, 24, 1), 256, 0, stream>>>(cwo, 0, 768, 768, coT, 0, 0);
    wtrans<<<dim3(24, 12, 1), 256, 0, stream>>>(fh_w1, 0, 768, 384, fh1T, 0, 0);
    wtrans<<<dim3(24, 12, 1), 256, 0, stream>>>(vh_w1, 0, 768, 384, vh1T, 0, 0);
    wtrans<<<dim3(24, 12, 1), 256, 0, stream>>>(ch_w1, 0, 768, 384, ch1T, 0, 0);
    f2b_k<<<2304, 256, 0, stream>>>(conv_w, convT, 589824L);   // conv_w is already [N=768][K=768]

    // ---- patch embedding ----
    patch_gather<<<13824, 256, 0, stream>>>(x, abuf);
    gemm_bt<128, EPI_PATCH><<<dim3(36, 6, 1), 256, 0, stream>>>(
        abuf, 768, 0, 0, convT, 768, 0, 0, 768, 1,
        dummy, 768, 0, 0, conv_b, nullptr, nullptr, h, pos_emb, nullptr, nullptr);
    cls_fix<<<12, 256, 0, stream>>>(cls_tok, pos_emb, h);

    // ---- transformer blocks ----
    for (int l = 0; l < 12; l++) {
        ln_k<<<1152, 256, 0, stream>>>(h, ln1g + l * 768, ln1b + l * 768, abuf);
        gemm_bt<128, EPI_QKV><<<dim3(36, 18, 1), 256, 0, stream>>>(
            abuf, 768, 0, 0, wqkvT + (long)l * 2304 * 768, 768, 0, 0, 768, 1,
            qb, 768, 0, 0, bq + l * 768, bk + l * 768, bv + l * 768,
            nullptr, nullptr, kb, vb);
        vtrans<<<dim3(18, 48), 256, 0, stream>>>(vb, vt);
        gemm_bt<128, EPI_BF16><<<dim3(9, 9, 48), 256, 0, stream>>>(
            qb, 768, 1152L * 768, 64, kb, 768, 1152L * 768, 64, 64, 12,
            sbuf, 1152, 12L * 1152 * 1152, 1152L * 1152,
            nullptr, nullptr, nullptr, nullptr, nullptr, nullptr, nullptr);
        softmax_k<<<13824, 256, 0, stream>>>(sbuf);
        gemm_bt<64, EPI_BF16><<<dim3(9, 1, 48), 128, 0, stream>>>(
            sbuf, 1152, 12L * 1152 * 1152, 1152L * 1152,
            vt, 1152, 12L * 64 * 1152, 64L * 1152, 1152, 12,
            ctx, 768, 1152L * 768, 64,
            nullptr, nullptr, nullptr, nullptr, nullptr, nullptr, nullptr);
        gemm_bt<128, EPI_RES><<<dim3(36, 6, 1), 256, 0, stream>>>(
            ctx, 768, 0, 0, woT + (long)l * 768 * 768, 768, 0, 0, 768, 1,
            dummy, 768, 0, 0, bo + l * 768, nullptr, nullptr, h, nullptr, nullptr, nullptr);
        ln_k<<<1152, 256, 0, stream>>>(h, ln2g + l * 768, ln2b + l * 768, abuf);
        gemm_bt<128, EPI_GELU><<<dim3(36, 24, 1), 256, 0, stream>>>(
            abuf, 768, 0, 0, w1T + (long)l * 3072 * 768, 768, 0, 0, 768, 1,
            gbuf, 3072, 0, 0, b1 + l * 3072, nullptr, nullptr, nullptr, nullptr, nullptr, nullptr);
        gemm_bt<128, EPI_RES><<<dim3(36, 6, 1), 256, 0, stream>>>(
            gbuf, 3072, 0, 0, w2T + (long)l * 768 * 3072, 3072, 0, 0, 3072, 1,
            dummy, 768, 0, 0, b2 + l * 768, nullptr, nullptr, h, nullptr, nullptr, nullptr);
    }

    // ---- cross-attention (q = kv = feats, no LN, no residual) ----
    f2b_k<<<13824, 256, 0, stream>>>(h, fbuf, 4608L * 768);
    gemm_bt<128, EPI_QKV><<<dim3(36, 18, 1), 256, 0, stream>>>(
        fbuf, 768, 0, 0, cqkvT, 768, 0, 0, 768, 1,
        qb, 768, 0, 0, cbq, cbk, cbv, nullptr, nullptr, kb, vb);
    vtrans<<<dim3(18, 48), 256, 0, stream>>>(vb, vt);
    gemm_bt<128, EPI_BF16><<<dim3(9, 9, 48), 256, 0, stream>>>(
        qb, 768, 1152L * 768, 64, kb, 768, 1152L * 768, 64, 64, 12,
        sbuf, 1152, 12L * 1152 * 1152, 1152L * 1152,
        nullptr, nullptr, nullptr, nullptr, nullptr, nullptr, nullptr);
    softmax_k<<<13824, 256, 0, stream>>>(sbuf);
    gemm_bt<64, EPI_BF16><<<dim3(9, 1, 48), 128, 0, stream>>>(
        sbuf, 1152, 12L * 1152 * 1152, 1152L * 1152,
        vt, 1152, 12L * 64 * 1152, 64L * 1152, 1152, 12,
        ctx, 768, 1152L * 768, 64,
        nullptr, nullptr, nullptr, nullptr, nullptr, nullptr, nullptr);
    gemm_bt<128, EPI_BIAS><<<dim3(36, 6, 1), 256, 0, stream>>>(
        ctx, 768, 0, 0, coT, 768, 0, 0, 768, 1,
        vfbuf, 768, 0, 0, cbo, nullptr, nullptr, nullptr, nullptr, nullptr, nullptr);

    // ---- heads ----
    gemm_bt<128, EPI_GELU><<<dim3(36, 3, 1), 256, 0, stream>>>(
        fbuf, 768, 0, 0, fh1T, 768, 0, 0, 768, 1,
        hid, 384, 0, 0, fh_b1, nullptr, nullptr, nullptr, nullptr, nullptr, nullptr);
    logits_k<<<33, 256, 0, stream>>>(hid, fh_w2, fh_b2, out + 0, 2);
    gemm_bt<128, EPI_GELU><<<dim3(36, 3, 1), 256, 0, stream>>>(
        vfbuf, 768, 0, 0, vh1T, 768, 0, 0, 768, 1,
        hid, 384, 0, 0, vh_b1, nullptr, nullptr, nullptr, nullptr, nullptr, nullptr);
    logits_k<<<65, 256, 0, stream>>>(hid, vh_w2, vh_b2, out + 8200, 4);
    gemm_bt<128, EPI_GELU><<<dim3(36, 3, 1), 256, 0, stream>>>(
        vfbuf, 768, 0, 0, ch1T, 768, 0, 0, 768, 1,
        hid, 384, 0, 0, ch_b1, nullptr, nullptr, nullptr, nullptr, nullptr, nullptr);
    logits_k<<<49, 256, 0, stream>>>(hid, ch_w2, ch_b2, out + 24600, 3);

    feats_out<<<3075, 256, 0, stream>>>(h, out + 36900);

    (void)in_sizes; (void)n_in; (void)out_size; (void)ws_size;
}

// Round 2
// 4609.038 us; speedup vs baseline: 1.0558x; 1.0558x over previous
//
#include <hip/hip_runtime.h>

// ============================================================
// CustomUltrasoundViT: 12-layer ViT (B=4, S=1025->pad 1152, D=768, H=12, HD=64,
// MLP=3072) + cross-attn + 3 heads. bf16 MFMA GEMMs, fp32 residual stream.
// R2: flash attention (no materialized scores), split-K for skinny RES GEMMs.
// ============================================================

typedef __attribute__((ext_vector_type(8))) short short8;
typedef __attribute__((ext_vector_type(4))) float floatx4;

#define EPI_BF16  0
#define EPI_BIAS  1
#define EPI_QKV   2
#define EPI_RES   3
#define EPI_GELU  4
#define EPI_PATCH 5

__device__ __forceinline__ short f2bf(float f) {
    union { float f; unsigned u; } x; x.f = f;
    return (short)((x.u + 0x7fffu + ((x.u >> 16) & 1u)) >> 16);
}
__device__ __forceinline__ float bf2f(short s) {
    union { unsigned u; float f; } x; x.u = ((unsigned)(unsigned short)s) << 16;
    return x.f;
}
__device__ __forceinline__ float gelu_f(float x) {
    return 0.5f * x * (1.f + erff(x * 0.70710678118654752f));
}
__device__ __forceinline__ void gload_lds16(const void* g, void* l) {
    __builtin_amdgcn_global_load_lds((const __attribute__((address_space(1))) void*)g,
                                     (__attribute__((address_space(3))) void*)l, 16, 0, 0);
}

// ------------------------------------------------------------
// gemm_bt: C[M,N] = A[M,K] @ BT[N,K]^T   (both row-major bf16-as-short)
// z-dim: ptr += (z/zdiv)*s1 + (z%zdiv)*s2 for A, B, O.  Split-K mode: zdiv=1,
// az1/bz1 = K-chunk element offsets, EPI_RES atomicAdds (bias from split 0).
// ------------------------------------------------------------
template<int BN, int EPI>
__global__ __launch_bounds__(BN == 128 ? 256 : 128)
void gemm_bt(const short* __restrict__ A, int lda, long az1, long az2,
             const short* __restrict__ Bt, int ldb, long bz1, long bz2,
             int K, int zdiv,
             short* __restrict__ O, int ldo, long oz1, long oz2,
             const float* __restrict__ bias0, const float* __restrict__ bias1,
             const float* __restrict__ bias2, float* __restrict__ hres,
             const float* __restrict__ pos,
             short* __restrict__ kout, short* __restrict__ vout)
{
    constexpr int NT = (BN == 128) ? 256 : 128;
    constexpr int ALOADS = 8192 / (NT * 16);        // A tile: 128x32x2B
    constexpr int BLOADS = (BN * 64) / (NT * 16);   // B tile: BNx32x2B
    __shared__ __align__(16) short As[128 * 32];
    __shared__ __align__(16) short Bs[BN * 32];

    const int tid = threadIdx.x;
    const int z = blockIdx.z;
    const int zq = z / zdiv, zr = z - zq * zdiv;
    A  += (long)zq * az1 + (long)zr * az2;
    Bt += (long)zq * bz1 + (long)zr * bz2;

    const int m0 = blockIdx.x * 128, n0 = blockIdx.y * BN;
    const int wave = tid >> 6, lane = tid & 63;
    const int quad = lane >> 4, l15 = lane & 15;
    const int wm = (BN == 128) ? (wave >> 1) : wave;
    const int wn = (BN == 128) ? (wave & 1) : 0;
    const int srow = tid >> 2;          // staging row within chunk
    const int scol = (tid & 3) * 8;     // staging col (elements)

    floatx4 acc[4][4];
    #pragma unroll
    for (int i = 0; i < 4; i++)
        #pragma unroll
        for (int j = 0; j < 4; j++)
            acc[i][j] = floatx4{0.f, 0.f, 0.f, 0.f};

    char* asBase = (char*)As + wave * 1024;   // wave-uniform LDS dest base
    char* bsBase = (char*)Bs + wave * 1024;
    const short* Ag = A + (long)(m0 + srow) * lda + scol;
    const short* Bg = Bt + (long)(n0 + srow) * ldb + scol;

    for (int k0 = 0; k0 < K; k0 += 32) {
        #pragma unroll
        for (int i = 0; i < ALOADS; i++)
            gload_lds16(Ag + (long)(i * (NT / 4)) * lda + k0, asBase + i * (NT * 16));
        #pragma unroll
        for (int i = 0; i < BLOADS; i++)
            gload_lds16(Bg + (long)(i * (NT / 4)) * ldb + k0, bsBase + i * (NT * 16));
        __syncthreads();
        short8 af[4], bfr[4];
        #pragma unroll
        for (int i = 0; i < 4; i++)
            af[i] = *(const short8*)&As[(wm * 64 + i * 16 + l15) * 32 + quad * 8];
        #pragma unroll
        for (int j = 0; j < 4; j++)
            bfr[j] = *(const short8*)&Bs[(wn * 64 + j * 16 + l15) * 32 + quad * 8];
        #pragma unroll
        for (int i = 0; i < 4; i++)
            #pragma unroll
            for (int j = 0; j < 4; j++)
                acc[i][j] = __builtin_amdgcn_mfma_f32_16x16x32_bf16(af[i], bfr[j], acc[i][j], 0, 0, 0);
        __syncthreads();
    }

    O += (long)zq * oz1 + (long)zr * oz2;
    const int mb = m0 + wm * 64 + quad * 4;
    const int nb = n0 + wn * 64 + l15;
    #pragma unroll
    for (int i = 0; i < 4; i++) {
        #pragma unroll
        for (int j = 0; j < 4; j++) {
            #pragma unroll
            for (int r = 0; r < 4; r++) {
                const int m = mb + i * 16 + r;
                const int n = nb + j * 16;
                const float c = acc[i][j][r];
                if constexpr (EPI == EPI_BF16) {
                    O[(long)m * ldo + n] = f2bf(c);
                } else if constexpr (EPI == EPI_BIAS) {
                    O[(long)m * ldo + n] = f2bf(c + bias0[n]);
                } else if constexpr (EPI == EPI_QKV) {
                    if (n < 768)            O[(long)m * 768 + n]            = f2bf((c + bias0[n]) * 0.125f);
                    else if (n < 1536)      kout[(long)m * 768 + (n - 768)]  = f2bf(c + bias1[n - 768]);
                    else                    vout[(long)m * 768 + (n - 1536)] = f2bf(c + bias2[n - 1536]);
                } else if constexpr (EPI == EPI_RES) {
                    atomicAdd(&hres[(long)m * 768 + n], c + (zq == 0 ? bias0[n] : 0.f));
                } else if constexpr (EPI == EPI_GELU) {
                    O[(long)m * ldo + n] = f2bf(gelu_f(c + bias0[n]));
                } else if constexpr (EPI == EPI_PATCH) {
                    const int tok = m % 1152;
                    float v = 0.f;
                    if (tok >= 1 && tok < 1025)
                        v = c + bias0[n] + pos[(long)tok * 768 + n];
                    hres[(long)m * 768 + n] = v;
                }
            }
        }
    }
}

// ------------------------------------------------------------
// flash attention: one block = 64 Q rows of one (b,h); 4 waves x 16 rows.
// Online softmax over 17 K-tiles of 64 (s < 1088; mask s >= 1025).
// Q pre-scaled by 1/8 in QKV epilogue. K from kb [4608][768] slice,
// V^T from vt [48][64][1152].  Output ctx [4608][768] bf16.
// LDS: K/V double-buffered (32 KB) + per-wave P transpose pad-40 (10 KB).
// ------------------------------------------------------------
__global__ __launch_bounds__(256)
void flash_attn(const short* __restrict__ qb, const short* __restrict__ kb,
                const short* __restrict__ vt, short* __restrict__ ctx)
{
    __shared__ __align__(16) short Ks[2][4096];   // [buf][c2][row64][k32]
    __shared__ __align__(16) short Vs[2][4096];   // [buf][c2][d64][k32]
    __shared__ __align__(16) short Ps[4][1280];   // [wave][c2][m16][k40 pad]

    const int tid = threadIdx.x;
    const int wave = tid >> 6, lane = tid & 63;
    const int quad = lane >> 4, l15 = lane & 15;
    const int bh = blockIdx.y, b = bh / 12, hh = bh - b * 12;
    const int q0 = blockIdx.x * 64;

    const long krow0 = (long)(b * 1152) * 768 + hh * 64;
    const long vrow0 = (long)(bh * 64) * 1152;
    const int srow = tid >> 2, scol8 = tid & 3;   // staging decode

    // Q fragments (A-layout), kept for the whole sweep
    short8 qa[2];
    {
        const int qrow = b * 1152 + q0 + wave * 16 + l15;
        const short* qp = qb + (long)qrow * 768 + hh * 64 + quad * 8;
        qa[0] = *(const short8*)qp;
        qa[1] = *(const short8*)(qp + 32);
    }

    floatx4 acco[4];
    #pragma unroll
    for (int j = 0; j < 4; j++) acco[j] = floatx4{0.f, 0.f, 0.f, 0.f};
    float m_i[4], l_i[4];
    #pragma unroll
    for (int r = 0; r < 4; r++) { m_i[r] = -1e30f; l_i[r] = 0.f; }

    auto stage = [&](int kt, int buf) {
        #pragma unroll
        for (int it = 0; it < 2; it++) {
            const short* kg = kb + krow0 + (long)(kt * 64 + srow) * 768 + it * 32 + scol8 * 8;
            gload_lds16(kg, (char*)&Ks[buf][0] + (it * 256 + wave * 64) * 16);
            const short* vg = vt + vrow0 + (long)srow * 1152 + kt * 64 + it * 32 + scol8 * 8;
            gload_lds16(vg, (char*)&Vs[buf][0] + (it * 256 + wave * 64) * 16);
        }
    };

    stage(0, 0);
    for (int kt = 0; kt < 17; kt++) {
        const int cur = kt & 1;
        __syncthreads();                       // stage(kt) landed; prev PV reads done
        if (kt + 1 < 17) stage(kt + 1, cur ^ 1);

        // ---- S = Q K^T (16 q-rows x 64 s-cols per wave) ----
        floatx4 accs[4];
        #pragma unroll
        for (int j = 0; j < 4; j++) accs[j] = floatx4{0.f, 0.f, 0.f, 0.f};
        #pragma unroll
        for (int c = 0; c < 2; c++)
            #pragma unroll
            for (int j = 0; j < 4; j++) {
                short8 kf = *(const short8*)&Ks[cur][c * 2048 + (j * 16 + l15) * 32 + quad * 8];
                accs[j] = __builtin_amdgcn_mfma_f32_16x16x32_bf16(qa[c], kf, accs[j], 0, 0, 0);
            }
        if (kt == 16) {   // s = 1024 + j*16 + l15 ; only s==1024 valid
            #pragma unroll
            for (int j = 0; j < 4; j++)
                if (j != 0 || l15 != 0) {
                    #pragma unroll
                    for (int r = 0; r < 4; r++) accs[j][r] = -1e30f;
                }
        }

        // ---- online softmax (rows owned per (quad,r), stats via l15 shuffles) ----
        float alpha[4], rs[4];
        #pragma unroll
        for (int r = 0; r < 4; r++) {
            float mx = fmaxf(fmaxf(accs[0][r], accs[1][r]), fmaxf(accs[2][r], accs[3][r]));
            #pragma unroll
            for (int off = 1; off < 16; off <<= 1) mx = fmaxf(mx, __shfl_xor(mx, off, 64));
            float newm = fmaxf(m_i[r], mx);
            alpha[r] = __expf(m_i[r] - newm);
            m_i[r] = newm;
            rs[r] = 0.f;
        }
        #pragma unroll
        for (int j = 0; j < 4; j++)
            #pragma unroll
            for (int r = 0; r < 4; r++) {
                float p = __expf(accs[j][r] - m_i[r]);
                rs[r] += p;
                Ps[wave][(j >> 1) * 640 + (quad * 4 + r) * 40 + (j & 1) * 16 + l15] = f2bf(p);
            }
        #pragma unroll
        for (int r = 0; r < 4; r++) {
            float s = rs[r];
            #pragma unroll
            for (int off = 1; off < 16; off <<= 1) s += __shfl_xor(s, off, 64);
            l_i[r] = alpha[r] * l_i[r] + s;
        }
        #pragma unroll
        for (int j = 0; j < 4; j++)
            #pragma unroll
            for (int r = 0; r < 4; r++) acco[j][r] *= alpha[r];

        __syncthreads();                       // P visible (and stage(kt+1) drained)

        // ---- O += P V ----
        #pragma unroll
        for (int c = 0; c < 2; c++) {
            short8 pa = *(const short8*)&Ps[wave][c * 640 + l15 * 40 + quad * 8];
            #pragma unroll
            for (int j = 0; j < 4; j++) {
                short8 vf = *(const short8*)&Vs[cur][c * 2048 + (j * 16 + l15) * 32 + quad * 8];
                acco[j] = __builtin_amdgcn_mfma_f32_16x16x32_bf16(pa, vf, acco[j], 0, 0, 0);
            }
        }
    }

    const int orow = b * 1152 + q0 + wave * 16 + quad * 4;
    #pragma unroll
    for (int r = 0; r < 4; r++) {
        float inv = 1.f / l_i[r];
        #pragma unroll
        for (int j = 0; j < 4; j++)
            ctx[(long)(orow + r) * 768 + hh * 64 + j * 16 + l15] = f2bf(acco[j][r] * inv);
    }
}

// ------------------------------------------------------------
// weight transpose + fp32->bf16: out[(rowoff+n)*K + k] = in[k*N + n]
// ------------------------------------------------------------
__global__ void wtrans(const float* __restrict__ in, long inls, int K, int N,
                       short* __restrict__ out, long outls, int rowoff)
{
    in  += (long)blockIdx.z * inls;
    out += (long)blockIdx.z * outls;
    const int k0 = blockIdx.x * 32, n0 = blockIdx.y * 32;
    const int tx = threadIdx.x & 31, ty = threadIdx.x >> 5;  // ty: 0..7
    __shared__ float t[32][33];
    #pragma unroll
    for (int i = 0; i < 4; i++)
        t[ty + i * 8][tx] = in[(long)(k0 + ty + i * 8) * N + n0 + tx];
    __syncthreads();
    #pragma unroll
    for (int i = 0; i < 4; i++)
        out[(long)(rowoff + n0 + ty + i * 8) * K + k0 + tx] = f2bf(t[tx][ty + i * 8]);
}

__global__ void f2b_k(const float* __restrict__ in, short* __restrict__ out, long n)
{
    long gid = (long)blockIdx.x * 256 + threadIdx.x;
    if (gid < n) out[gid] = f2bf(in[gid]);
}

// patch gather: A[m][k] = x[b][c][py*16+i][px*16+j]; m=b*1152+tok, k=c*256+i*16+j
__global__ void patch_gather(const float* __restrict__ x, short* __restrict__ out)
{
    long gid = (long)blockIdx.x * 256 + threadIdx.x;   // 4608*768 total
    int m = (int)(gid / 768), k = (int)(gid % 768);
    int b = m / 1152, tok = m % 1152;
    short v = 0;
    if (tok >= 1 && tok < 1025) {
        int pidx = tok - 1, py = pidx >> 5, px = pidx & 31;
        int c = k >> 8, rem = k & 255, ii = rem >> 4, jj = rem & 15;
        float f = x[((long)(b * 3 + c) * 512 + py * 16 + ii) * 512 + px * 16 + jj];
        v = f2bf(f);
    }
    out[gid] = v;
}

__global__ void cls_fix(const float* __restrict__ cls, const float* __restrict__ pos,
                        float* __restrict__ h)
{
    int t = blockIdx.x * 256 + threadIdx.x;   // 4*768
    if (t >= 4 * 768) return;
    int b = t / 768, d = t % 768;
    h[(long)b * 1152 * 768 + d] = cls[d] + pos[d];
}

// LayerNorm fp32 -> bf16 out; one wave per row, 4 rows/block
__global__ void ln_k(const float* __restrict__ h, const float* __restrict__ g,
                     const float* __restrict__ bta, short* __restrict__ out)
{
    int row = blockIdx.x * 4 + (threadIdx.x >> 6);
    int lane = threadIdx.x & 63;
    const float* hr = h + (long)row * 768;
    float v[12], s = 0.f;
    #pragma unroll
    for (int i = 0; i < 12; i++) { v[i] = hr[i * 64 + lane]; s += v[i]; }
    #pragma unroll
    for (int o = 32; o > 0; o >>= 1) s += __shfl_xor(s, o, 64);
    float mean = s * (1.f / 768.f);
    float ss = 0.f;
    #pragma unroll
    for (int i = 0; i < 12; i++) { float d = v[i] - mean; ss += d * d; }
    #pragma unroll
    for (int o = 32; o > 0; o >>= 1) ss += __shfl_xor(ss, o, 64);
    float rstd = rsqrtf(ss * (1.f / 768.f) + 1e-5f);
    #pragma unroll
    for (int i = 0; i < 12; i++) {
        int col = i * 64 + lane;
        out[(long)row * 768 + col] = f2bf((v[i] - mean) * rstd * g[col] + bta[col]);
    }
}

// vt[bh][d][s] = v[(b*1152+s)*768 + h*64 + d]; grid (1152/64, 48), block 256
__global__ void vtrans(const short* __restrict__ v, short* __restrict__ vt)
{
    int bh = blockIdx.y, b = bh / 12, hh = bh % 12;
    int s0 = blockIdx.x * 64;
    int tx = threadIdx.x & 63, ty = threadIdx.x >> 6;  // ty: 0..3
    __shared__ short t[64][65];
    #pragma unroll
    for (int i = 0; i < 16; i++) {
        int sl = ty * 16 + i;
        t[sl][tx] = v[(long)(b * 1152 + s0 + sl) * 768 + hh * 64 + tx];
    }
    __syncthreads();
    #pragma unroll
    for (int i = 0; i < 16; i++) {
        int d = ty * 16 + i;
        vt[((long)bh * 64 + d) * 1152 + s0 + tx] = t[tx][d];
    }
}

// tiny head GEMM: out[bs*NO+n] = b2[n] + sum_k hid[m,k]*w2[k,n]
__global__ void logits_k(const short* __restrict__ hid, const float* __restrict__ w2,
                         const float* __restrict__ b2, float* __restrict__ o, int NO)
{
    int gid = blockIdx.x * 256 + threadIdx.x;
    if (gid >= 4100 * NO) return;
    int bs = gid / NO, n = gid % NO;
    int b = bs / 1025, s = bs % 1025;
    const short* hr = hid + (long)(b * 1152 + s) * 384;
    float acc = b2[n];
    for (int k = 0; k < 384; k++) acc += bf2f(hr[k]) * w2[k * NO + n];
    o[gid] = acc;
}

__global__ void feats_out(const float* __restrict__ h, float* __restrict__ o)
{
    int gid = blockIdx.x * 256 + threadIdx.x;   // 4*1025*192
    if (gid >= 4 * 1025 * 192) return;
    int row = gid / 192, c4 = gid % 192;
    int b = row / 1025, s = row % 1025;
    const float4* src = (const float4*)(h + (long)(b * 1152 + s) * 768) + c4;
    float4* dst = (float4*)(o + (long)row * 768) + c4;
    *dst = *src;
}

// ============================================================
extern "C" void kernel_launch(void* const* d_in, const int* in_sizes, int n_in,
                              void* d_out, int out_size, void* d_ws, size_t ws_size,
                              hipStream_t stream)
{
    const float* x       = (const float*)d_in[0];
    const float* conv_w  = (const float*)d_in[1];
    const float* conv_b  = (const float*)d_in[2];
    const float* cls_tok = (const float*)d_in[3];
    const float* pos_emb = (const float*)d_in[4];
    const float* ln1g = (const float*)d_in[5];
    const float* ln1b = (const float*)d_in[6];
    const float* wq = (const float*)d_in[7];
    const float* bq = (const float*)d_in[8];
    const float* wk = (const float*)d_in[9];
    const float* bk = (const float*)d_in[10];
    const float* wv = (const float*)d_in[11];
    const float* bv = (const float*)d_in[12];
    const float* wo = (const float*)d_in[13];
    const float* bo = (const float*)d_in[14];
    const float* ln2g = (const float*)d_in[15];
    const float* ln2b = (const float*)d_in[16];
    const float* w1 = (const float*)d_in[17];
    const float* b1 = (const float*)d_in[18];
    const float* w2 = (const float*)d_in[19];
    const float* b2 = (const float*)d_in[20];
    const float* cwq = (const float*)d_in[21];
    const float* cbq = (const float*)d_in[22];
    const float* cwk = (const float*)d_in[23];
    const float* cbk = (const float*)d_in[24];
    const float* cwv = (const float*)d_in[25];
    const float* cbv = (const float*)d_in[26];
    const float* cwo = (const float*)d_in[27];
    const float* cbo = (const float*)d_in[28];
    const float* fh_w1 = (const float*)d_in[29];
    const float* fh_b1 = (const float*)d_in[30];
    const float* fh_w2 = (const float*)d_in[31];
    const float* fh_b2 = (const float*)d_in[32];
    const float* vh_w1 = (const float*)d_in[33];
    const float* vh_b1 = (const float*)d_in[34];
    const float* vh_w2 = (const float*)d_in[35];
    const float* vh_b2 = (const float*)d_in[36];
    const float* ch_w1 = (const float*)d_in[37];
    const float* ch_b1 = (const float*)d_in[38];
    const float* ch_w2 = (const float*)d_in[39];
    const float* ch_b2 = (const float*)d_in[40];
    float* out = (float*)d_out;

    // ---- workspace carve-up ----
    char* ws = (char*)d_ws;
    size_t off = 0;
    auto alc = [&](size_t b) { char* p = ws + off; off += (b + 255) & ~(size_t)255; return p; };
    float* h     = (float*)alc(4608L * 768 * 4);
    short* abuf  = (short*)alc(4608L * 768 * 2);
    short* gbuf  = (short*)alc(4608L * 3072 * 2);
    short* qb    = (short*)alc(4608L * 768 * 2);
    short* kb    = (short*)alc(4608L * 768 * 2);
    short* vb    = (short*)alc(4608L * 768 * 2);
    short* vt    = (short*)alc(48L * 64 * 1152 * 2);
    short* ctx   = (short*)alc(4608L * 768 * 2);
    short* fbuf  = (short*)alc(4608L * 768 * 2);
    short* vfbuf = (short*)alc(4608L * 768 * 2);
    short* hid   = (short*)alc(4608L * 384 * 2);
    short* wqkvT = (short*)alc(12L * 2304 * 768 * 2);
    short* woT   = (short*)alc(12L * 768 * 768 * 2);
    short* w1T   = (short*)alc(12L * 3072 * 768 * 2);
    short* w2T   = (short*)alc(12L * 768 * 3072 * 2);
    short* convT = (short*)alc(768L * 768 * 2);
    short* cqkvT = (short*)alc(2304L * 768 * 2);
    short* coT   = (short*)alc(768L * 768 * 2);
    short* fh1T  = (short*)alc(384L * 768 * 2);
    short* vh1T  = (short*)alc(384L * 768 * 2);
    short* ch1T  = (short*)alc(384L * 768 * 2);
    short* dummy = (short*)d_ws;

    // ---- weight prep (bf16 transposed [N,K]) ----
    wtrans<<<dim3(24, 24, 12), 256, 0, stream>>>(wq, 589824L, 768, 768, wqkvT, 1769472L, 0);
    wtrans<<<dim3(24, 24, 12), 256, 0, stream>>>(wk, 589824L, 768, 768, wqkvT, 1769472L, 768);
    wtrans<<<dim3(24, 24, 12), 256, 0, stream>>>(wv, 589824L, 768, 768, wqkvT, 1769472L, 1536);
    wtrans<<<dim3(24, 24, 12), 256, 0, stream>>>(wo, 589824L, 768, 768, woT, 589824L, 0);
    wtrans<<<dim3(24, 96, 12), 256, 0, stream>>>(w1, 2359296L, 768, 3072, w1T, 2359296L, 0);
    wtrans<<<dim3(96, 24, 12), 256, 0, stream>>>(w2, 2359296L, 3072, 768, w2T, 2359296L, 0);
    wtrans<<<dim3(24, 24, 1), 256, 0, stream>>>(cwq, 0, 768, 768, cqkvT, 0, 0);
    wtrans<<<dim3(24, 24, 1), 256, 0, stream>>>(cwk, 0, 768, 768, cqkvT, 0, 768);
    wtrans<<<dim3(24, 24, 1), 256, 0, stream>>>(cwv, 0, 768, 768, cqkvT, 0, 1536);
    wtrans<<<dim3(24, 24, 1), 256, 0, stream>>>(cwo, 0, 768, 768, coT, 0, 0);
    wtrans<<<dim3(24, 12, 1), 256, 0, stream>>>(fh_w1, 0, 768, 384, fh1T, 0, 0);
    wtrans<<<dim3(24, 12, 1), 256, 0, stream>>>(vh_w1, 0, 768, 384, vh1T, 0, 0);
    wtrans<<<dim3(24, 12, 1), 256, 0, stream>>>(ch_w1, 0, 768, 384, ch1T, 0, 0);
    f2b_k<<<2304, 256, 0, stream>>>(conv_w, convT, 589824L);   // conv_w already [N][K]

    // ---- patch embedding ----
    patch_gather<<<13824, 256, 0, stream>>>(x, abuf);
    gemm_bt<128, EPI_PATCH><<<dim3(36, 6, 1), 256, 0, stream>>>(
        abuf, 768, 0, 0, convT, 768, 0, 0, 768, 1,
        dummy, 768, 0, 0, conv_b, nullptr, nullptr, h, pos_emb, nullptr, nullptr);
    cls_fix<<<12, 256, 0, stream>>>(cls_tok, pos_emb, h);

    // ---- transformer blocks ----
    for (int l = 0; l < 12; l++) {
        ln_k<<<1152, 256, 0, stream>>>(h, ln1g + l * 768, ln1b + l * 768, abuf);
        gemm_bt<128, EPI_QKV><<<dim3(36, 18, 1), 256, 0, stream>>>(
            abuf, 768, 0, 0, wqkvT + (long)l * 2304 * 768, 768, 0, 0, 768, 1,
            qb, 768, 0, 0, bq + l * 768, bk + l * 768, bv + l * 768,
            nullptr, nullptr, kb, vb);
        vtrans<<<dim3(18, 48), 256, 0, stream>>>(vb, vt);
        flash_attn<<<dim3(18, 48), 256, 0, stream>>>(qb, kb, vt, ctx);
        gemm_bt<128, EPI_RES><<<dim3(36, 6, 2), 256, 0, stream>>>(   // proj, split-K x2
            ctx, 768, 384, 0, woT + (long)l * 768 * 768, 768, 384, 0, 384, 1,
            dummy, 768, 0, 0, bo + l * 768, nullptr, nullptr, h, nullptr, nullptr, nullptr);
        ln_k<<<1152, 256, 0, stream>>>(h, ln2g + l * 768, ln2b + l * 768, abuf);
        gemm_bt<128, EPI_GELU><<<dim3(36, 24, 1), 256, 0, stream>>>(
            abuf, 768, 0, 0, w1T + (long)l * 3072 * 768, 768, 0, 0, 768, 1,
            gbuf, 3072, 0, 0, b1 + l * 3072, nullptr, nullptr, nullptr, nullptr, nullptr, nullptr);
        gemm_bt<128, EPI_RES><<<dim3(36, 6, 4), 256, 0, stream>>>(   // MLP2, split-K x4
            gbuf, 3072, 768, 0, w2T + (long)l * 768 * 3072, 3072, 768, 0, 768, 1,
            dummy, 768, 0, 0, b2 + l * 768, nullptr, nullptr, h, nullptr, nullptr, nullptr);
    }

    // ---- cross-attention (q = kv = feats, no LN, no residual) ----
    f2b_k<<<13824, 256, 0, stream>>>(h, fbuf, 4608L * 768);
    gemm_bt<128, EPI_QKV><<<dim3(36, 18, 1), 256, 0, stream>>>(
        fbuf, 768, 0, 0, cqkvT, 768, 0, 0, 768, 1,
        qb, 768, 0, 0, cbq, cbk, cbv, nullptr, nullptr, kb, vb);
    vtrans<<<dim3(18, 48), 256, 0, stream>>>(vb, vt);
    flash_attn<<<dim3(18, 48), 256, 0, stream>>>(qb, kb, vt, ctx);
    gemm_bt<128, EPI_BIAS><<<dim3(36, 6, 1), 256, 0, stream>>>(
        ctx, 768, 0, 0, coT, 768, 0, 0, 768, 1,
        vfbuf, 768, 0, 0, cbo, nullptr, nullptr, nullptr, nullptr, nullptr, nullptr);

    // ---- heads ----
    gemm_bt<128, EPI_GELU><<<dim3(36, 3, 1), 256, 0, stream>>>(
        fbuf, 768, 0, 0, fh1T, 768, 0, 0, 768, 1,
        hid, 384, 0, 0, fh_b1, nullptr, nullptr, nullptr, nullptr, nullptr, nullptr);
    logits_k<<<33, 256, 0, stream>>>(hid, fh_w2, fh_b2, out + 0, 2);
    gemm_bt<128, EPI_GELU><<<dim3(36, 3, 1), 256, 0, stream>>>(
        vfbuf, 768, 0, 0, vh1T, 768, 0, 0, 768, 1,
        hid, 384, 0, 0, vh_b1, nullptr, nullptr, nullptr, nullptr, nullptr, nullptr);
    logits_k<<<65, 256, 0, stream>>>(hid, vh_w2, vh_b2, out + 8200, 4);
    gemm_bt<128, EPI_GELU><<<dim3(36, 3, 1), 256, 0, stream>>>(
        vfbuf, 768, 0, 0, ch1T, 768, 0, 0, 768, 1,
        hid, 384, 0, 0, ch_b1, nullptr, nullptr, nullptr, nullptr, nullptr, nullptr);
    logits_k<<<49, 256, 0, stream>>>(hid, ch_w2, ch_b2, out + 24600, 3);

    feats_out<<<3075, 256, 0, stream>>>(h, out + 36900);

    (void)in_sizes; (void)n_in; (void)out_size; (void)ws_size;
}

// Round 3
// 3538.735 us; speedup vs baseline: 1.3751x; 1.3025x over previous
//
#include <hip/hip_runtime.h>

// ============================================================
// CustomUltrasoundViT: 12-layer ViT (B=4, S=1025->pad 1152, D=768, H=12, HD=64,
// MLP=3072) + cross-attn + 3 heads. bf16 MFMA GEMMs, fp32 residual stream.
// R3: register-staged + LDS double-buffered GEMM K-loop (one barrier/iter,
// prefetch loads stay in flight across barriers); 128x64 tiles for N=768
// GEMMs (no split-K atomics).
// ============================================================

typedef __attribute__((ext_vector_type(8))) short short8;
typedef __attribute__((ext_vector_type(4))) float floatx4;

#define EPI_BF16  0
#define EPI_BIAS  1
#define EPI_QKV   2
#define EPI_RES   3
#define EPI_GELU  4
#define EPI_PATCH 5

__device__ __forceinline__ short f2bf(float f) {
    union { float f; unsigned u; } x; x.f = f;
    return (short)((x.u + 0x7fffu + ((x.u >> 16) & 1u)) >> 16);
}
__device__ __forceinline__ float bf2f(short s) {
    union { unsigned u; float f; } x; x.u = ((unsigned)(unsigned short)s) << 16;
    return x.f;
}
__device__ __forceinline__ float gelu_f(float x) {
    return 0.5f * x * (1.f + erff(x * 0.70710678118654752f));
}
__device__ __forceinline__ void gload_lds16(const void* g, void* l) {
    __builtin_amdgcn_global_load_lds((const __attribute__((address_space(1))) void*)g,
                                     (__attribute__((address_space(3))) void*)l, 16, 0, 0);
}

// ------------------------------------------------------------
// gemm_bt: C[M,N] = A[M,K] @ BT[N,K]^T (row-major bf16-as-short).
// BM=128. BN=128: 4 waves 2x2 (64x64 each). BN=64: 4 waves 2x2 (64x32 each).
// K-loop: global->VGPR prefetch (2 tiles deep, survives barriers) ->
// ds_write -> single barrier -> ds_read frags -> MFMA. LDS double-buffered.
// ------------------------------------------------------------
template<int BN, int EPI>
__global__ __launch_bounds__(256)
void gemm_bt(const short* __restrict__ A, int lda,
             const short* __restrict__ Bt, int ldb, int K,
             short* __restrict__ O, int ldo,
             const float* __restrict__ bias0, const float* __restrict__ bias1,
             const float* __restrict__ bias2, float* __restrict__ hres,
             const float* __restrict__ pos,
             short* __restrict__ kout, short* __restrict__ vout)
{
    constexpr int BCH = BN / 64;                 // B-tile 16B chunks per thread
    constexpr int WNS = (BN == 128) ? 64 : 32;   // wave N span
    constexpr int NJ  = WNS / 16;
    __shared__ __align__(16) short As[2][128 * 32];
    __shared__ __align__(16) short Bs[2][BN * 32];

    const int tid = threadIdx.x;
    const int m0 = blockIdx.x * 128, n0 = blockIdx.y * BN;
    const int wave = tid >> 6, lane = tid & 63;
    const int quad = lane >> 4, l15 = lane & 15;
    const int wm = wave >> 1, wn = wave & 1;
    const int srow = tid >> 2, scol = (tid & 3) * 8;

    const short* Ag = A + (long)(m0 + srow) * lda + scol;
    const short* Bg = Bt + (long)(n0 + srow) * ldb + scol;

    const int NIT = K >> 5;                      // always even, >= 12
    short8 ra[2][2], rb[2][BCH];
    #pragma unroll
    for (int pp = 0; pp < 2; pp++) {
        #pragma unroll
        for (int c = 0; c < 2; c++)
            ra[pp][c] = *(const short8*)(Ag + (long)(64 * c) * lda + pp * 32);
        #pragma unroll
        for (int c = 0; c < BCH; c++)
            rb[pp][c] = *(const short8*)(Bg + (long)(64 * c) * ldb + pp * 32);
    }

    floatx4 acc[4][NJ];
    #pragma unroll
    for (int i = 0; i < 4; i++)
        #pragma unroll
        for (int j = 0; j < NJ; j++)
            acc[i][j] = floatx4{0.f, 0.f, 0.f, 0.f};

    auto step = [&](int it, int pp) {
        short* as = As[pp];
        short* bs = Bs[pp];
        // regs -> LDS (tile it)
        #pragma unroll
        for (int c = 0; c < 2; c++)
            *(short8*)&as[(srow + 64 * c) * 32 + scol] = ra[pp][c];
        #pragma unroll
        for (int c = 0; c < BCH; c++)
            *(short8*)&bs[(srow + 64 * c) * 32 + scol] = rb[pp][c];
        __syncthreads();
        // issue global loads for tile it+2 (private regs: not drained by barriers)
        if (it + 2 < NIT) {
            const int k0 = (it + 2) * 32;
            #pragma unroll
            for (int c = 0; c < 2; c++)
                ra[pp][c] = *(const short8*)(Ag + (long)(64 * c) * lda + k0);
            #pragma unroll
            for (int c = 0; c < BCH; c++)
                rb[pp][c] = *(const short8*)(Bg + (long)(64 * c) * ldb + k0);
        }
        // LDS -> frags -> MFMA
        short8 af[4], bfrag[NJ];
        #pragma unroll
        for (int i = 0; i < 4; i++)
            af[i] = *(const short8*)&as[(wm * 64 + i * 16 + l15) * 32 + quad * 8];
        #pragma unroll
        for (int j = 0; j < NJ; j++)
            bfrag[j] = *(const short8*)&bs[(wn * WNS + j * 16 + l15) * 32 + quad * 8];
        #pragma unroll
        for (int i = 0; i < 4; i++)
            #pragma unroll
            for (int j = 0; j < NJ; j++)
                acc[i][j] = __builtin_amdgcn_mfma_f32_16x16x32_bf16(af[i], bfrag[j], acc[i][j], 0, 0, 0);
        // no trailing barrier: next iter writes the other LDS buffer
    };

    #pragma unroll 1
    for (int it = 0; it < NIT; it += 2) {
        step(it, 0);
        step(it + 1, 1);
    }

    const int mb = m0 + wm * 64 + quad * 4;
    const int nb = n0 + wn * WNS + l15;
    #pragma unroll
    for (int i = 0; i < 4; i++) {
        #pragma unroll
        for (int j = 0; j < NJ; j++) {
            #pragma unroll
            for (int r = 0; r < 4; r++) {
                const int m = mb + i * 16 + r;
                const int n = nb + j * 16;
                const float c = acc[i][j][r];
                if constexpr (EPI == EPI_BF16) {
                    O[(long)m * ldo + n] = f2bf(c);
                } else if constexpr (EPI == EPI_BIAS) {
                    O[(long)m * ldo + n] = f2bf(c + bias0[n]);
                } else if constexpr (EPI == EPI_QKV) {
                    if (n < 768)            O[(long)m * 768 + n]             = f2bf((c + bias0[n]) * 0.125f);
                    else if (n < 1536)      kout[(long)m * 768 + (n - 768)]  = f2bf(c + bias1[n - 768]);
                    else                    vout[(long)m * 768 + (n - 1536)] = f2bf(c + bias2[n - 1536]);
                } else if constexpr (EPI == EPI_RES) {
                    hres[(long)m * 768 + n] += c + bias0[n];
                } else if constexpr (EPI == EPI_GELU) {
                    O[(long)m * ldo + n] = f2bf(gelu_f(c + bias0[n]));
                } else if constexpr (EPI == EPI_PATCH) {
                    const int tok = m % 1152;
                    float v = 0.f;
                    if (tok >= 1 && tok < 1025)
                        v = c + bias0[n] + pos[(long)tok * 768 + n];
                    hres[(long)m * 768 + n] = v;
                }
            }
        }
    }
}

// ------------------------------------------------------------
// flash attention: one block = 64 Q rows of one (b,h); 4 waves x 16 rows.
// Online softmax over 17 K-tiles of 64 (mask s >= 1025). Q pre-scaled 1/8.
// ------------------------------------------------------------
__global__ __launch_bounds__(256)
void flash_attn(const short* __restrict__ qb, const short* __restrict__ kb,
                const short* __restrict__ vt, short* __restrict__ ctx)
{
    __shared__ __align__(16) short Ks[2][4096];
    __shared__ __align__(16) short Vs[2][4096];
    __shared__ __align__(16) short Ps[4][1280];

    const int tid = threadIdx.x;
    const int wave = tid >> 6, lane = tid & 63;
    const int quad = lane >> 4, l15 = lane & 15;
    const int bh = blockIdx.y, b = bh / 12, hh = bh - b * 12;
    const int q0 = blockIdx.x * 64;

    const long krow0 = (long)(b * 1152) * 768 + hh * 64;
    const long vrow0 = (long)(bh * 64) * 1152;
    const int srow = tid >> 2, scol8 = tid & 3;

    short8 qa[2];
    {
        const int qrow = b * 1152 + q0 + wave * 16 + l15;
        const short* qp = qb + (long)qrow * 768 + hh * 64 + quad * 8;
        qa[0] = *(const short8*)qp;
        qa[1] = *(const short8*)(qp + 32);
    }

    floatx4 acco[4];
    #pragma unroll
    for (int j = 0; j < 4; j++) acco[j] = floatx4{0.f, 0.f, 0.f, 0.f};
    float m_i[4], l_i[4];
    #pragma unroll
    for (int r = 0; r < 4; r++) { m_i[r] = -1e30f; l_i[r] = 0.f; }

    auto stage = [&](int kt, int buf) {
        #pragma unroll
        for (int it = 0; it < 2; it++) {
            const short* kg = kb + krow0 + (long)(kt * 64 + srow) * 768 + it * 32 + scol8 * 8;
            gload_lds16(kg, (char*)&Ks[buf][0] + (it * 256 + wave * 64) * 16);
            const short* vg = vt + vrow0 + (long)srow * 1152 + kt * 64 + it * 32 + scol8 * 8;
            gload_lds16(vg, (char*)&Vs[buf][0] + (it * 256 + wave * 64) * 16);
        }
    };

    stage(0, 0);
    for (int kt = 0; kt < 17; kt++) {
        const int cur = kt & 1;
        __syncthreads();
        if (kt + 1 < 17) stage(kt + 1, cur ^ 1);

        floatx4 accs[4];
        #pragma unroll
        for (int j = 0; j < 4; j++) accs[j] = floatx4{0.f, 0.f, 0.f, 0.f};
        #pragma unroll
        for (int c = 0; c < 2; c++)
            #pragma unroll
            for (int j = 0; j < 4; j++) {
                short8 kf = *(const short8*)&Ks[cur][c * 2048 + (j * 16 + l15) * 32 + quad * 8];
                accs[j] = __builtin_amdgcn_mfma_f32_16x16x32_bf16(qa[c], kf, accs[j], 0, 0, 0);
            }
        if (kt == 16) {
            #pragma unroll
            for (int j = 0; j < 4; j++)
                if (j != 0 || l15 != 0) {
                    #pragma unroll
                    for (int r = 0; r < 4; r++) accs[j][r] = -1e30f;
                }
        }

        float alpha[4], rs[4];
        #pragma unroll
        for (int r = 0; r < 4; r++) {
            float mx = fmaxf(fmaxf(accs[0][r], accs[1][r]), fmaxf(accs[2][r], accs[3][r]));
            #pragma unroll
            for (int off = 1; off < 16; off <<= 1) mx = fmaxf(mx, __shfl_xor(mx, off, 64));
            float newm = fmaxf(m_i[r], mx);
            alpha[r] = __expf(m_i[r] - newm);
            m_i[r] = newm;
            rs[r] = 0.f;
        }
        #pragma unroll
        for (int j = 0; j < 4; j++)
            #pragma unroll
            for (int r = 0; r < 4; r++) {
                float p = __expf(accs[j][r] - m_i[r]);
                rs[r] += p;
                Ps[wave][(j >> 1) * 640 + (quad * 4 + r) * 40 + (j & 1) * 16 + l15] = f2bf(p);
            }
        #pragma unroll
        for (int r = 0; r < 4; r++) {
            float s = rs[r];
            #pragma unroll
            for (int off = 1; off < 16; off <<= 1) s += __shfl_xor(s, off, 64);
            l_i[r] = alpha[r] * l_i[r] + s;
        }
        #pragma unroll
        for (int j = 0; j < 4; j++)
            #pragma unroll
            for (int r = 0; r < 4; r++) acco[j][r] *= alpha[r];

        __syncthreads();

        #pragma unroll
        for (int c = 0; c < 2; c++) {
            short8 pa = *(const short8*)&Ps[wave][c * 640 + l15 * 40 + quad * 8];
            #pragma unroll
            for (int j = 0; j < 4; j++) {
                short8 vf = *(const short8*)&Vs[cur][c * 2048 + (j * 16 + l15) * 32 + quad * 8];
                acco[j] = __builtin_amdgcn_mfma_f32_16x16x32_bf16(pa, vf, acco[j], 0, 0, 0);
            }
        }
    }

    const int orow = b * 1152 + q0 + wave * 16 + quad * 4;
    #pragma unroll
    for (int r = 0; r < 4; r++) {
        float inv = 1.f / l_i[r];
        #pragma unroll
        for (int j = 0; j < 4; j++)
            ctx[(long)(orow + r) * 768 + hh * 64 + j * 16 + l15] = f2bf(acco[j][r] * inv);
    }
}

// ------------------------------------------------------------
__global__ void wtrans(const float* __restrict__ in, long inls, int K, int N,
                       short* __restrict__ out, long outls, int rowoff)
{
    in  += (long)blockIdx.z * inls;
    out += (long)blockIdx.z * outls;
    const int k0 = blockIdx.x * 32, n0 = blockIdx.y * 32;
    const int tx = threadIdx.x & 31, ty = threadIdx.x >> 5;
    __shared__ float t[32][33];
    #pragma unroll
    for (int i = 0; i < 4; i++)
        t[ty + i * 8][tx] = in[(long)(k0 + ty + i * 8) * N + n0 + tx];
    __syncthreads();
    #pragma unroll
    for (int i = 0; i < 4; i++)
        out[(long)(rowoff + n0 + ty + i * 8) * K + k0 + tx] = f2bf(t[tx][ty + i * 8]);
}

__global__ void f2b_k(const float* __restrict__ in, short* __restrict__ out, long n)
{
    long gid = (long)blockIdx.x * 256 + threadIdx.x;
    if (gid < n) out[gid] = f2bf(in[gid]);
}

__global__ void patch_gather(const float* __restrict__ x, short* __restrict__ out)
{
    long gid = (long)blockIdx.x * 256 + threadIdx.x;
    int m = (int)(gid / 768), k = (int)(gid % 768);
    int b = m / 1152, tok = m % 1152;
    short v = 0;
    if (tok >= 1 && tok < 1025) {
        int pidx = tok - 1, py = pidx >> 5, px = pidx & 31;
        int c = k >> 8, rem = k & 255, ii = rem >> 4, jj = rem & 15;
        float f = x[((long)(b * 3 + c) * 512 + py * 16 + ii) * 512 + px * 16 + jj];
        v = f2bf(f);
    }
    out[gid] = v;
}

__global__ void cls_fix(const float* __restrict__ cls, const float* __restrict__ pos,
                        float* __restrict__ h)
{
    int t = blockIdx.x * 256 + threadIdx.x;
    if (t >= 4 * 768) return;
    int b = t / 768, d = t % 768;
    h[(long)b * 1152 * 768 + d] = cls[d] + pos[d];
}

__global__ void ln_k(const float* __restrict__ h, const float* __restrict__ g,
                     const float* __restrict__ bta, short* __restrict__ out)
{
    int row = blockIdx.x * 4 + (threadIdx.x >> 6);
    int lane = threadIdx.x & 63;
    const float* hr = h + (long)row * 768;
    float v[12], s = 0.f;
    #pragma unroll
    for (int i = 0; i < 12; i++) { v[i] = hr[i * 64 + lane]; s += v[i]; }
    #pragma unroll
    for (int o = 32; o > 0; o >>= 1) s += __shfl_xor(s, o, 64);
    float mean = s * (1.f / 768.f);
    float ss = 0.f;
    #pragma unroll
    for (int i = 0; i < 12; i++) { float d = v[i] - mean; ss += d * d; }
    #pragma unroll
    for (int o = 32; o > 0; o >>= 1) ss += __shfl_xor(ss, o, 64);
    float rstd = rsqrtf(ss * (1.f / 768.f) + 1e-5f);
    #pragma unroll
    for (int i = 0; i < 12; i++) {
        int col = i * 64 + lane;
        out[(long)row * 768 + col] = f2bf((v[i] - mean) * rstd * g[col] + bta[col]);
    }
}

__global__ void vtrans(const short* __restrict__ v, short* __restrict__ vt)
{
    int bh = blockIdx.y, b = bh / 12, hh = bh % 12;
    int s0 = blockIdx.x * 64;
    int tx = threadIdx.x & 63, ty = threadIdx.x >> 6;
    __shared__ short t[64][65];
    #pragma unroll
    for (int i = 0; i < 16; i++) {
        int sl = ty * 16 + i;
        t[sl][tx] = v[(long)(b * 1152 + s0 + sl) * 768 + hh * 64 + tx];
    }
    __syncthreads();
    #pragma unroll
    for (int i = 0; i < 16; i++) {
        int d = ty * 16 + i;
        vt[((long)bh * 64 + d) * 1152 + s0 + tx] = t[tx][d];
    }
}

__global__ void logits_k(const short* __restrict__ hid, const float* __restrict__ w2,
                         const float* __restrict__ b2, float* __restrict__ o, int NO)
{
    int gid = blockIdx.x * 256 + threadIdx.x;
    if (gid >= 4100 * NO) return;
    int bs = gid / NO, n = gid % NO;
    int b = bs / 1025, s = bs % 1025;
    const short* hr = hid + (long)(b * 1152 + s) * 384;
    float acc = b2[n];
    for (int k = 0; k < 384; k++) acc += bf2f(hr[k]) * w2[k * NO + n];
    o[gid] = acc;
}

__global__ void feats_out(const float* __restrict__ h, float* __restrict__ o)
{
    int gid = blockIdx.x * 256 + threadIdx.x;
    if (gid >= 4 * 1025 * 192) return;
    int row = gid / 192, c4 = gid % 192;
    int b = row / 1025, s = row % 1025;
    const float4* src = (const float4*)(h + (long)(b * 1152 + s) * 768) + c4;
    float4* dst = (float4*)(o + (long)row * 768) + c4;
    *dst = *src;
}

// ============================================================
extern "C" void kernel_launch(void* const* d_in, const int* in_sizes, int n_in,
                              void* d_out, int out_size, void* d_ws, size_t ws_size,
                              hipStream_t stream)
{
    const float* x       = (const float*)d_in[0];
    const float* conv_w  = (const float*)d_in[1];
    const float* conv_b  = (const float*)d_in[2];
    const float* cls_tok = (const float*)d_in[3];
    const float* pos_emb = (const float*)d_in[4];
    const float* ln1g = (const float*)d_in[5];
    const float* ln1b = (const float*)d_in[6];
    const float* wq = (const float*)d_in[7];
    const float* bq = (const float*)d_in[8];
    const float* wk = (const float*)d_in[9];
    const float* bk = (const float*)d_in[10];
    const float* wv = (const float*)d_in[11];
    const float* bv = (const float*)d_in[12];
    const float* wo = (const float*)d_in[13];
    const float* bo = (const float*)d_in[14];
    const float* ln2g = (const float*)d_in[15];
    const float* ln2b = (const float*)d_in[16];
    const float* w1 = (const float*)d_in[17];
    const float* b1 = (const float*)d_in[18];
    const float* w2 = (const float*)d_in[19];
    const float* b2 = (const float*)d_in[20];
    const float* cwq = (const float*)d_in[21];
    const float* cbq = (const float*)d_in[22];
    const float* cwk = (const float*)d_in[23];
    const float* cbk = (const float*)d_in[24];
    const float* cwv = (const float*)d_in[25];
    const float* cbv = (const float*)d_in[26];
    const float* cwo = (const float*)d_in[27];
    const float* cbo = (const float*)d_in[28];
    const float* fh_w1 = (const float*)d_in[29];
    const float* fh_b1 = (const float*)d_in[30];
    const float* fh_w2 = (const float*)d_in[31];
    const float* fh_b2 = (const float*)d_in[32];
    const float* vh_w1 = (const float*)d_in[33];
    const float* vh_b1 = (const float*)d_in[34];
    const float* vh_w2 = (const float*)d_in[35];
    const float* vh_b2 = (const float*)d_in[36];
    const float* ch_w1 = (const float*)d_in[37];
    const float* ch_b1 = (const float*)d_in[38];
    const float* ch_w2 = (const float*)d_in[39];
    const float* ch_b2 = (const float*)d_in[40];
    float* out = (float*)d_out;

    // ---- workspace carve-up ----
    char* ws = (char*)d_ws;
    size_t off = 0;
    auto alc = [&](size_t b) { char* p = ws + off; off += (b + 255) & ~(size_t)255; return p; };
    float* h     = (float*)alc(4608L * 768 * 4);
    short* abuf  = (short*)alc(4608L * 768 * 2);
    short* gbuf  = (short*)alc(4608L * 3072 * 2);
    short* qb    = (short*)alc(4608L * 768 * 2);
    short* kb    = (short*)alc(4608L * 768 * 2);
    short* vb    = (short*)alc(4608L * 768 * 2);
    short* vt    = (short*)alc(48L * 64 * 1152 * 2);
    short* ctx   = (short*)alc(4608L * 768 * 2);
    short* fbuf  = (short*)alc(4608L * 768 * 2);
    short* vfbuf = (short*)alc(4608L * 768 * 2);
    short* hid   = (short*)alc(4608L * 384 * 2);
    short* wqkvT = (short*)alc(12L * 2304 * 768 * 2);
    short* woT   = (short*)alc(12L * 768 * 768 * 2);
    short* w1T   = (short*)alc(12L * 3072 * 768 * 2);
    short* w2T   = (short*)alc(12L * 768 * 3072 * 2);
    short* convT = (short*)alc(768L * 768 * 2);
    short* cqkvT = (short*)alc(2304L * 768 * 2);
    short* coT   = (short*)alc(768L * 768 * 2);
    short* fh1T  = (short*)alc(384L * 768 * 2);
    short* vh1T  = (short*)alc(384L * 768 * 2);
    short* ch1T  = (short*)alc(384L * 768 * 2);
    short* dummy = (short*)d_ws;

    // ---- weight prep (bf16 transposed [N,K]) ----
    wtrans<<<dim3(24, 24, 12), 256, 0, stream>>>(wq, 589824L, 768, 768, wqkvT, 1769472L, 0);
    wtrans<<<dim3(24, 24, 12), 256, 0, stream>>>(wk, 589824L, 768, 768, wqkvT, 1769472L, 768);
    wtrans<<<dim3(24, 24, 12), 256, 0, stream>>>(wv, 589824L, 768, 768, wqkvT, 1769472L, 1536);
    wtrans<<<dim3(24, 24, 12), 256, 0, stream>>>(wo, 589824L, 768, 768, woT, 589824L, 0);
    wtrans<<<dim3(24, 96, 12), 256, 0, stream>>>(w1, 2359296L, 768, 3072, w1T, 2359296L, 0);
    wtrans<<<dim3(96, 24, 12), 256, 0, stream>>>(w2, 2359296L, 3072, 768, w2T, 2359296L, 0);
    wtrans<<<dim3(24, 24, 1), 256, 0, stream>>>(cwq, 0, 768, 768, cqkvT, 0, 0);
    wtrans<<<dim3(24, 24, 1), 256, 0, stream>>>(cwk, 0, 768, 768, cqkvT, 0, 768);
    wtrans<<<dim3(24, 24, 1), 256, 0, stream>>>(cwv, 0, 768, 768, cqkvT, 0, 1536);
    wtrans<<<dim3(24, 24, 1), 256, 0, stream>>>(cwo, 0, 768, 768, coT, 0, 0);
    wtrans<<<dim3(24, 12, 1), 256, 0, stream>>>(fh_w1, 0, 768, 384, fh1T, 0, 0);
    wtrans<<<dim3(24, 12, 1), 256, 0, stream>>>(vh_w1, 0, 768, 384, vh1T, 0, 0);
    wtrans<<<dim3(24, 12, 1), 256, 0, stream>>>(ch_w1, 0, 768, 384, ch1T, 0, 0);
    f2b_k<<<2304, 256, 0, stream>>>(conv_w, convT, 589824L);

    // ---- patch embedding ----
    patch_gather<<<13824, 256, 0, stream>>>(x, abuf);
    gemm_bt<64, EPI_PATCH><<<dim3(36, 12), 256, 0, stream>>>(
        abuf, 768, convT, 768, 768,
        dummy, 768, conv_b, nullptr, nullptr, h, pos_emb, nullptr, nullptr);
    cls_fix<<<12, 256, 0, stream>>>(cls_tok, pos_emb, h);

    // ---- transformer blocks ----
    for (int l = 0; l < 12; l++) {
        ln_k<<<1152, 256, 0, stream>>>(h, ln1g + l * 768, ln1b + l * 768, abuf);
        gemm_bt<128, EPI_QKV><<<dim3(36, 18), 256, 0, stream>>>(
            abuf, 768, wqkvT + (long)l * 2304 * 768, 768, 768,
            qb, 768, bq + l * 768, bk + l * 768, bv + l * 768,
            nullptr, nullptr, kb, vb);
        vtrans<<<dim3(18, 48), 256, 0, stream>>>(vb, vt);
        flash_attn<<<dim3(18, 48), 256, 0, stream>>>(qb, kb, vt, ctx);
        gemm_bt<64, EPI_RES><<<dim3(36, 12), 256, 0, stream>>>(
            ctx, 768, woT + (long)l * 768 * 768, 768, 768,
            dummy, 768, bo + l * 768, nullptr, nullptr, h, nullptr, nullptr, nullptr);
        ln_k<<<1152, 256, 0, stream>>>(h, ln2g + l * 768, ln2b + l * 768, abuf);
        gemm_bt<128, EPI_GELU><<<dim3(36, 24), 256, 0, stream>>>(
            abuf, 768, w1T + (long)l * 3072 * 768, 768, 768,
            gbuf, 3072, b1 + l * 3072, nullptr, nullptr, nullptr, nullptr, nullptr, nullptr);
        gemm_bt<64, EPI_RES><<<dim3(36, 12), 256, 0, stream>>>(
            gbuf, 3072, w2T + (long)l * 768 * 3072, 3072, 3072,
            dummy, 768, b2 + l * 768, nullptr, nullptr, h, nullptr, nullptr, nullptr);
    }

    // ---- cross-attention ----
    f2b_k<<<13824, 256, 0, stream>>>(h, fbuf, 4608L * 768);
    gemm_bt<128, EPI_QKV><<<dim3(36, 18), 256, 0, stream>>>(
        fbuf, 768, cqkvT, 768, 768,
        qb, 768, cbq, cbk, cbv, nullptr, nullptr, kb, vb);
    vtrans<<<dim3(18, 48), 256, 0, stream>>>(vb, vt);
    flash_attn<<<dim3(18, 48), 256, 0, stream>>>(qb, kb, vt, ctx);
    gemm_bt<64, EPI_BIAS><<<dim3(36, 12), 256, 0, stream>>>(
        ctx, 768, coT, 768, 768,
        vfbuf, 768, cbo, nullptr, nullptr, nullptr, nullptr, nullptr, nullptr);

    // ---- heads ----
    gemm_bt<64, EPI_GELU><<<dim3(36, 6), 256, 0, stream>>>(
        fbuf, 768, fh1T, 768, 768,
        hid, 384, fh_b1, nullptr, nullptr, nullptr, nullptr, nullptr, nullptr);
    logits_k<<<33, 256, 0, stream>>>(hid, fh_w2, fh_b2, out + 0, 2);
    gemm_bt<64, EPI_GELU><<<dim3(36, 6), 256, 0, stream>>>(
        vfbuf, 768, vh1T, 768, 768,
        hid, 384, vh_b1, nullptr, nullptr, nullptr, nullptr, nullptr, nullptr);
    logits_k<<<65, 256, 0, stream>>>(hid, vh_w2, vh_b2, out + 8200, 4);
    gemm_bt<64, EPI_GELU><<<dim3(36, 6), 256, 0, stream>>>(
        vfbuf, 768, ch1T, 768, 768,
        hid, 384, ch_b1, nullptr, nullptr, nullptr, nullptr, nullptr, nullptr);
    logits_k<<<49, 256, 0, stream>>>(hid, ch_w2, ch_b2, out + 24600, 3);

    feats_out<<<3075, 256, 0, stream>>>(h, out + 36900);

    (void)in_sizes; (void)n_in; (void)out_size; (void)ws_size;
}